// Round 4
// baseline (4743.175 us; speedup 1.0000x reference)
//
#include <hip/hip_runtime.h>
#include <stdint.h>

typedef unsigned long long u64;

#define NB   32
#define TST  384
#define IDM  64
#define HDM  128
#define NCLS 10
#define EPSF 1e-7f
#define LOG2E 1.44269504088896340736f

// LDS float offsets
#define O_SBUF 0      // 388 (385 used) cached s_buf
#define O_WLDS 388    // 388 attention weights per position
#define O_DELT 776    // 32 deltas from all batches
#define O_MISC 808    // 24: [0..8) s_h partials, [8..16) wsp, [16..24) tb
#define O_MASK 832    // 16 floats = 8 u64 ballot masks (byte 3328, 8B-aligned)
#define O_ACT  848    // 192: x_t(64) | h(128)
#define O_GEX  1040   // 256: FC feature [h | attn]
#define O_RED  1296   // 1024: per-wave attn partials (8 x 128)
#define O_WFC  2320   // 10*264 = 2640 padded W_fc
#define O_BFC  4960   // 12
#define SMTOT  4972

__device__ __forceinline__ float sigm(float x) {
  return 1.0f / (1.0f + __builtin_amdgcn_exp2f(-LOG2E * x));
}
__device__ __forceinline__ float tanh_f(float x) {
  return 1.0f - 2.0f / (1.0f + __builtin_amdgcn_exp2f(2.0f * LOG2E * x));
}
// full-rate DPP add: v += lane-shuffled v (ctrl is an ICE via template)
template <int CTRL>
__device__ __forceinline__ float dppadd(float v) {
  int t = __builtin_amdgcn_update_dpp(0, __builtin_bit_cast(int, v), CTRL, 0xF, 0xF, true);
  return v + __builtin_bit_cast(float, t);
}
// wave64 sum: xor1,xor2 (quad_perm), xor4 (half-mirror), xor8 (mirror), then 16/32
__device__ __forceinline__ float wave_sum(float v) {
  v = dppadd<0xB1>(v);   // quad_perm [1,0,3,2]
  v = dppadd<0x4E>(v);   // quad_perm [2,3,0,1]
  v = dppadd<0x141>(v);  // row_half_mirror (xor4: quads uniform)
  v = dppadd<0x140>(v);  // row_mirror      (xor8: octets uniform)
  v += __shfl_xor(v, 16, 64);
  v += __shfl_xor(v, 32, 64);
  return v;
}
// reduce within aligned 16-lane group (for FC)
__device__ __forceinline__ float sum16(float v) {
  v = dppadd<0xB1>(v);
  v = dppadd<0x4E>(v);
  v = dppadd<0x141>(v);
  v = dppadd<0x140>(v);
  return v;
}

__global__ __launch_bounds__(512, 2)
void sab_kernel(const float* __restrict__ x, const float* __restrict__ Wih,
                const float* __restrict__ Whh, const float* __restrict__ bihp,
                const float* __restrict__ bhhp, const float* __restrict__ wtp,
                const float* __restrict__ Wfcp, const float* __restrict__ bfcp,
                float* __restrict__ dout, u64* __restrict__ mail) {
  __shared__ __align__(16) float SM[SMTOT];
  u64* MASK8 = (u64*)(SM + O_MASK);

  const int tid  = threadIdx.x;
  const int lane = tid & 63;
  const int wv   = tid >> 6;
  const int b    = blockIdx.x;
  const int j    = tid >> 2;          // hidden index 0..127
  const int s    = tid & 3;           // K-slice 0..3 (48 cols each)

  float* hsout = dout + (size_t)NB * TST * NCLS;   // hs region == attention buffer
  const float* myx = x + (size_t)b * TST * IDM;

  // ---- per-thread register weights: 4 gates x 48 K-cols ----
  float w[4][48];
  float bias[4];
  #pragma unroll
  for (int g = 0; g < 4; ++g) {
    const int row = g * HDM + j;
    #pragma unroll
    for (int kk = 0; kk < 48; ++kk) {
      const int k = 48 * s + kk;
      w[g][kk] = (k < IDM) ? Wih[row * IDM + k] : Whh[row * HDM + (k - IDM)];
    }
    bias[g] = bihp[row] + bhhp[row];
  }
  const float wt0 = wtp[j];
  const float wt1 = wtp[HDM + j];

  // top-5 of s_buf (tid 0 only meaningful); s_buf[0]=0 pre-inserted
  float t5a = 0.f, t5b = -3e38f, t5c = -3e38f, t5d = -3e38f, t5e = -3e38f;

  // ---- init LDS ----
  for (int i = tid; i < SMTOT; i += 512) SM[i] = 0.f;
  __syncthreads();
  for (int idx = tid; idx < NCLS * 256; idx += 512)
    SM[O_WFC + (idx >> 8) * 264 + (idx & 255)] = Wfcp[idx];
  if (tid < NCLS) SM[O_BFC + tid] = bfcp[tid];
  if (tid < IDM)  SM[O_ACT + tid] = myx[tid];     // x_0 (h zeroed above)
  if (tid == 0) {
    __hip_atomic_store(&mail[0 * NB + b], 0ull, __ATOMIC_RELAXED, __HIP_MEMORY_SCOPE_AGENT);
    __hip_atomic_store(&mail[1 * NB + b], 0ull, __ATOMIC_RELAXED, __HIP_MEMORY_SCOPE_AGENT);
  }
  __syncthreads();

  float cst = 0.f, hc = 0.f;

  for (int t = 0; t < TST; ++t) {
    const int r = t + 1;
    const bool big = (r > 5);

    // ================= gates + cell (quad-split K, no LDS, no barrier) =========
    float a0 = 0.f, a1 = 0.f, a2 = 0.f, a3 = 0.f;
    {
      const float4* a4 = reinterpret_cast<const float4*>(SM + O_ACT + 48 * s);
      #pragma unroll
      for (int m = 0; m < 12; ++m) {
        const float4 av = a4[m];
        a0 = fmaf(av.x, w[0][4*m+0], a0); a0 = fmaf(av.y, w[0][4*m+1], a0);
        a0 = fmaf(av.z, w[0][4*m+2], a0); a0 = fmaf(av.w, w[0][4*m+3], a0);
        a1 = fmaf(av.x, w[1][4*m+0], a1); a1 = fmaf(av.y, w[1][4*m+1], a1);
        a1 = fmaf(av.z, w[1][4*m+2], a1); a1 = fmaf(av.w, w[1][4*m+3], a1);
        a2 = fmaf(av.x, w[2][4*m+0], a2); a2 = fmaf(av.y, w[2][4*m+1], a2);
        a2 = fmaf(av.z, w[2][4*m+2], a2); a2 = fmaf(av.w, w[2][4*m+3], a2);
        a3 = fmaf(av.x, w[3][4*m+0], a3); a3 = fmaf(av.y, w[3][4*m+1], a3);
        a3 = fmaf(av.z, w[3][4*m+2], a3); a3 = fmaf(av.w, w[3][4*m+3], a3);
      }
    }
    // quad butterfly via DPP (full-rate VALU, not LDS pipe)
    a0 = dppadd<0xB1>(a0); a0 = dppadd<0x4E>(a0);
    a1 = dppadd<0xB1>(a1); a1 = dppadd<0x4E>(a1);
    a2 = dppadd<0xB1>(a2); a2 = dppadd<0x4E>(a2);
    a3 = dppadd<0xB1>(a3); a3 = dppadd<0x4E>(a3);
    const float iv = sigm(a0 + bias[0]);
    const float fv = sigm(a1 + bias[1]);
    const float gv = tanh_f(a2 + bias[2]);
    const float ov = sigm(a3 + bias[3]);
    cst = fv * cst + iv * gv;
    hc  = ov * tanh_f(cst);

    const float shp = wave_sum((s == 0) ? tanh_f(hc) * wt0 : 0.f);
    if (lane == 0) SM[O_MISC + wv] = shp;
    __syncthreads();                                        // B1

    float s_h = 0.f;
    #pragma unroll
    for (int i = 0; i < 8; ++i) s_h += SM[O_MISC + i];

    // ---- publish ASAP (tid0: finish s_buf[t], insert into top-5, publish) ----
    if (tid == 0) {
      if (t > 0) {
        float sb = 0.f;
        #pragma unroll
        for (int i = 0; i < 8; ++i) sb += SM[O_MISC + 16 + i];
        SM[O_SBUF + t] = sb;
        if (sb > t5e) {
          if (sb > t5a)      { t5e=t5d; t5d=t5c; t5c=t5b; t5b=t5a; t5a=sb; }
          else if (sb > t5b) { t5e=t5d; t5d=t5c; t5c=t5b; t5b=sb; }
          else if (sb > t5c) { t5e=t5d; t5d=t5c; t5c=sb; }
          else if (sb > t5d) { t5e=t5d; t5d=sb; }
          else               { t5e=sb; }
        }
      }
      if (big) {
        const u64 pv = (((u64)(unsigned)r) << 32) | (u64)__float_as_uint(t5e + s_h + EPSF);
        __hip_atomic_store(&mail[(r & 1) * NB + b], pv, __ATOMIC_RELAXED, __HIP_MEMORY_SCOPE_AGENT);
      }
    }

    // ---- tail work overlapped with the cross-XCD exchange flight ----
    float xr = 0.f;
    if (tid < IDM && t + 1 < TST) xr = myx[(size_t)(t + 1) * IDM + tid];
    if (t > 0 && tid < 160) {     // FC for step t-1 (reads GEX from prev iter)
      const int cls = tid >> 4, p = tid & 15;
      float pt = 0.f;
      #pragma unroll
      for (int i = 0; i < 16; ++i) {
        const int k = p + 16 * i;
        pt = fmaf(SM[O_WFC + cls * 264 + k], SM[O_GEX + k], pt);
      }
      pt = sum16(pt);
      if (p == 0) dout[(size_t)(b * TST + (t - 1)) * NCLS + cls] = pt + SM[O_BFC + cls];
    }

    // ---- poll (relaxed, contiguous slots: 4 cachelines) ----
    if (big && tid < NB) {
      u64* slot = &mail[(r & 1) * NB + tid];
      u64 v = __hip_atomic_load(slot, __ATOMIC_RELAXED, __HIP_MEMORY_SCOPE_AGENT);
      while ((unsigned)(v >> 32) != (unsigned)r) {
        __builtin_amdgcn_s_sleep(1);
        v = __hip_atomic_load(slot, __ATOMIC_RELAXED, __HIP_MEMORY_SCOPE_AGENT);
      }
      SM[O_DELT + tid] = __uint_as_float((unsigned)v);
    }
    __syncthreads();                                        // B2

    // ================= attention weights =================
    float wval = 0.f; bool pred = false;
    if (big) {
      if (tid < r) {
        const float sc = s_h + SM[O_SBUF + tid];
        wval = fmaxf(sc - SM[O_DELT + ((b * r + tid) & (NB - 1))], 0.f);
        pred = (wval > 0.f) && (tid > 0);
      }
    } else {
      float scv = (tid < r) ? (s_h + SM[O_SBUF + tid]) : -3e38f;
      float mx = scv;
      mx = fmaxf(mx, __shfl_xor(mx, 1, 64));  mx = fmaxf(mx, __shfl_xor(mx, 2, 64));
      mx = fmaxf(mx, __shfl_xor(mx, 4, 64));  mx = fmaxf(mx, __shfl_xor(mx, 8, 64));
      mx = fmaxf(mx, __shfl_xor(mx, 16, 64)); mx = fmaxf(mx, __shfl_xor(mx, 32, 64));
      if (tid < r) {
        wval = __builtin_amdgcn_exp2f(LOG2E * (scv - mx));
        pred = (tid > 0);
      }
    }
    if (tid < r) SM[O_WLDS + tid] = wval;   // FIX: guard — WLDS is 388 floats; an
                                            // unguarded 512-thread store clobbered
                                            // DELT/MISC/MASK/ACT (round-3 bug)
    const u64 m0 = __ballot((int)pred);
    if (lane == 0) MASK8[wv] = m0;
    const float wsp = wave_sum(wval);
    if (lane == 0) SM[O_MISC + 8 + wv] = wsp;
    __syncthreads();                                        // B3

    // ================= gather: rank-distributed across 8 waves =================
    // wave-uniform mask walk (scalar branches); each wave takes ranks == wv mod 8
    float g0 = 0.f, g1 = 0.f;
    {
      int rank = 0;
      #pragma unroll
      for (int wi = 0; wi < 8; ++wi) {
        u64 m = MASK8[wi];
        while (m) {
          const int l = __builtin_ctzll(m); m &= m - 1;
          if ((rank & 7) == wv) {
            const int tp = (wi << 6) + l;
            const float wgt = SM[O_WLDS + tp];
            const float2 v = reinterpret_cast<const float2*>(
                hsout + (size_t)(b * TST + tp - 1) * HDM)[lane];
            g0 = fmaf(wgt, v.x, g0);
            g1 = fmaf(wgt, v.y, g1);
          }
          ++rank;
        }
      }
    }
    reinterpret_cast<float2*>(SM + O_RED + wv * HDM)[lane] = make_float2(g0, g1);
    __syncthreads();                                        // B4

    // ================= finalize h, stores =================
    float wsum = 0.f;
    #pragma unroll
    for (int i = 0; i < 8; ++i) wsum += SM[O_MISC + 8 + i];
    const float inv = 1.0f / (wsum + (big ? EPSF : 0.0f));
    float attn = 0.f;
    #pragma unroll
    for (int wv2 = 0; wv2 < 8; ++wv2) attn += SM[O_RED + wv2 * HDM + j];
    attn *= inv;
    const float hf = hc + attn;
    if (s == 0) {
      SM[O_ACT + IDM + j] = hf;     // h for next step's gates
      SM[O_GEX + j] = hf;           // FC feature
      SM[O_GEX + HDM + j] = attn;
      hsout[(size_t)(b * TST + t) * HDM + j] = hf;
    }
    if (tid < IDM && t + 1 < TST) SM[O_ACT + tid] = xr;
    const float tbv = wave_sum((s == 0) ? tanh_f(hf) * wt1 : 0.f);
    if (lane == 0) SM[O_MISC + 16 + wv] = tbv;
    __syncthreads();                                        // B5 (loop end)
  }

  // final FC for t = 383
  if (tid < 160) {
    const int cls = tid >> 4, p = tid & 15;
    float pt = 0.f;
    #pragma unroll
    for (int i = 0; i < 16; ++i) {
      const int k = p + 16 * i;
      pt = fmaf(SM[O_WFC + cls * 264 + k], SM[O_GEX + k], pt);
    }
    pt = sum16(pt);
    if (p == 0) dout[(size_t)(b * TST + (TST - 1)) * NCLS + cls] = pt + SM[O_BFC + cls];
  }
}

extern "C" void kernel_launch(void* const* d_in, const int* in_sizes, int n_in,
                              void* d_out, int out_size, void* d_ws, size_t ws_size,
                              hipStream_t stream) {
  const float* x   = (const float*)d_in[0];
  const float* Wih = (const float*)d_in[1];
  const float* Whh = (const float*)d_in[2];
  const float* bih = (const float*)d_in[3];
  const float* bhh = (const float*)d_in[4];
  const float* wt  = (const float*)d_in[5];
  const float* Wfc = (const float*)d_in[6];
  const float* bfc = (const float*)d_in[7];
  sab_kernel<<<dim3(NB), dim3(512), 0, stream>>>(
      x, Wih, Whh, bih, bhh, wt, Wfc, bfc, (float*)d_out, (u64*)d_ws);
}

// Round 5
// 4004.506 us; speedup vs baseline: 1.1845x; 1.1845x over previous
//
#include <hip/hip_runtime.h>
#include <stdint.h>

typedef unsigned long long u64;

#define NB   32
#define TST  384
#define IDM  64
#define HDM  128
#define NCLS 10
#define EPSF 1e-7f
#define LOG2E 1.44269504088896340736f

// LDS float offsets
#define O_SBUF 0      // 385 used (pad 388) cached s_buf
#define O_DELT 388    // 32 deltas from all batches
#define O_MISC 420    // 24: [0..8) s_h partials, [8..16) wsp, [16..24) tb
#define O_ACT  448    // 192: x_t(64) | h(128)   (byte 1792, 16B-aligned)
#define O_GEX  640    // 256: FC feature [h | attn]
#define O_RED  896    // 1024: per-wave attn partials (8 x 128) (byte 3584)
#define O_WFC  1920   // 10*264 = 2640 padded W_fc
#define O_BFC  4560   // 12
#define SMTOT  4572

__device__ __forceinline__ float sigm(float x) {
  return 1.0f / (1.0f + __builtin_amdgcn_exp2f(-LOG2E * x));
}
__device__ __forceinline__ float tanh_f(float x) {
  return 1.0f - 2.0f / (1.0f + __builtin_amdgcn_exp2f(2.0f * LOG2E * x));
}
// full-rate DPP add: v += lane-shuffled v
template <int CTRL>
__device__ __forceinline__ float dppadd(float v) {
  int t = __builtin_amdgcn_update_dpp(0, __builtin_bit_cast(int, v), CTRL, 0xF, 0xF, true);
  return v + __builtin_bit_cast(float, t);
}
__device__ __forceinline__ float wave_sum(float v) {
  v = dppadd<0xB1>(v);   // quad_perm xor1
  v = dppadd<0x4E>(v);   // quad_perm xor2
  v = dppadd<0x141>(v);  // row_half_mirror (xor4)
  v = dppadd<0x140>(v);  // row_mirror      (xor8)
  v += __shfl_xor(v, 16, 64);
  v += __shfl_xor(v, 32, 64);
  return v;
}
__device__ __forceinline__ float sum16(float v) {
  v = dppadd<0xB1>(v);
  v = dppadd<0x4E>(v);
  v = dppadd<0x141>(v);
  v = dppadd<0x140>(v);
  return v;
}

__global__ __launch_bounds__(512, 2)
void sab_kernel(const float* __restrict__ x, const float* __restrict__ Wih,
                const float* __restrict__ Whh, const float* __restrict__ bihp,
                const float* __restrict__ bhhp, const float* __restrict__ wtp,
                const float* __restrict__ Wfcp, const float* __restrict__ bfcp,
                float* __restrict__ dout, u64* __restrict__ mail) {
  __shared__ __align__(16) float SM[SMTOT];

  const int tid  = threadIdx.x;
  const int lane = tid & 63;
  const int wv   = tid >> 6;
  const int b    = blockIdx.x;
  const int j    = tid >> 2;          // hidden index 0..127
  const int s    = tid & 3;           // K-slice 0..3 (48 cols each)

  float* hsout = dout + (size_t)NB * TST * NCLS;   // hs region == attention buffer
  const float* myx = x + (size_t)b * TST * IDM;

  // ---- per-thread register weights: 4 gates x 48 K-cols ----
  float w[4][48];
  float bias[4];
  #pragma unroll
  for (int g = 0; g < 4; ++g) {
    const int row = g * HDM + j;
    #pragma unroll
    for (int kk = 0; kk < 48; ++kk) {
      const int k = 48 * s + kk;
      w[g][kk] = (k < IDM) ? Wih[row * IDM + k] : Whh[row * HDM + (k - IDM)];
    }
    bias[g] = bihp[row] + bhhp[row];
  }
  const float wt0 = wtp[j];
  const float wt1 = wtp[HDM + j];

  // top-5 of s_buf (tid 0 only meaningful); s_buf[0]=0 pre-inserted
  float t5a = 0.f, t5b = -3e38f, t5c = -3e38f, t5d = -3e38f, t5e = -3e38f;

  // ---- init LDS ----
  for (int i = tid; i < SMTOT; i += 512) SM[i] = 0.f;
  __syncthreads();
  for (int idx = tid; idx < NCLS * 256; idx += 512)
    SM[O_WFC + (idx >> 8) * 264 + (idx & 255)] = Wfcp[idx];
  if (tid < NCLS) SM[O_BFC + tid] = bfcp[tid];
  if (tid < IDM)  SM[O_ACT + tid] = myx[tid];     // x_0 (h zeroed above)
  if (tid == 0) {
    __hip_atomic_store(&mail[0 * NB + b], 0ull, __ATOMIC_RELAXED, __HIP_MEMORY_SCOPE_AGENT);
    __hip_atomic_store(&mail[1 * NB + b], 0ull, __ATOMIC_RELAXED, __HIP_MEMORY_SCOPE_AGENT);
  }
  __syncthreads();

  float cst = 0.f, hc = 0.f;

  for (int t = 0; t < TST; ++t) {
    const int r = t + 1;
    const bool big = (r > 5);

    // ================= gates + cell (quad-split K, no LDS, no barrier) =========
    float a0 = 0.f, a1 = 0.f, a2 = 0.f, a3 = 0.f;
    {
      const float4* a4 = reinterpret_cast<const float4*>(SM + O_ACT + 48 * s);
      #pragma unroll
      for (int m = 0; m < 12; ++m) {
        const float4 av = a4[m];
        a0 = fmaf(av.x, w[0][4*m+0], a0); a0 = fmaf(av.y, w[0][4*m+1], a0);
        a0 = fmaf(av.z, w[0][4*m+2], a0); a0 = fmaf(av.w, w[0][4*m+3], a0);
        a1 = fmaf(av.x, w[1][4*m+0], a1); a1 = fmaf(av.y, w[1][4*m+1], a1);
        a1 = fmaf(av.z, w[1][4*m+2], a1); a1 = fmaf(av.w, w[1][4*m+3], a1);
        a2 = fmaf(av.x, w[2][4*m+0], a2); a2 = fmaf(av.y, w[2][4*m+1], a2);
        a2 = fmaf(av.z, w[2][4*m+2], a2); a2 = fmaf(av.w, w[2][4*m+3], a2);
        a3 = fmaf(av.x, w[3][4*m+0], a3); a3 = fmaf(av.y, w[3][4*m+1], a3);
        a3 = fmaf(av.z, w[3][4*m+2], a3); a3 = fmaf(av.w, w[3][4*m+3], a3);
      }
    }
    a0 = dppadd<0xB1>(a0); a0 = dppadd<0x4E>(a0);
    a1 = dppadd<0xB1>(a1); a1 = dppadd<0x4E>(a1);
    a2 = dppadd<0xB1>(a2); a2 = dppadd<0x4E>(a2);
    a3 = dppadd<0xB1>(a3); a3 = dppadd<0x4E>(a3);
    const float iv = sigm(a0 + bias[0]);
    const float fv = sigm(a1 + bias[1]);
    const float gv = tanh_f(a2 + bias[2]);
    const float ov = sigm(a3 + bias[3]);
    cst = fv * cst + iv * gv;
    hc  = ov * tanh_f(cst);

    const float shp = wave_sum((s == 0) ? tanh_f(hc) * wt0 : 0.f);
    if (lane == 0) SM[O_MISC + wv] = shp;
    __syncthreads();                                        // B1

    float s_h = 0.f;
    #pragma unroll
    for (int i = 0; i < 8; ++i) s_h += SM[O_MISC + i];

    // ---- publish ASAP (tid0: finalize s_buf[t], top-5 insert, RELEASE store) ----
    if (tid == 0) {
      if (t > 0) {
        float sb = 0.f;
        #pragma unroll
        for (int i = 0; i < 8; ++i) sb += SM[O_MISC + 16 + i];
        SM[O_SBUF + t] = sb;
        if (sb > t5e) {
          if (sb > t5a)      { t5e=t5d; t5d=t5c; t5c=t5b; t5b=t5a; t5a=sb; }
          else if (sb > t5b) { t5e=t5d; t5d=t5c; t5c=t5b; t5b=sb; }
          else if (sb > t5c) { t5e=t5d; t5d=t5c; t5c=sb; }
          else if (sb > t5d) { t5e=t5d; t5d=sb; }
          else               { t5e=sb; }
        }
      }
      if (big) {
        const u64 pv = (((u64)(unsigned)r) << 32) | (u64)__float_as_uint(t5e + s_h + EPSF);
        __hip_atomic_store(&mail[(r & 1) * NB + b], pv, __ATOMIC_RELEASE, __HIP_MEMORY_SCOPE_AGENT);
      }
    }
    // keep later loads from being hoisted above the release store (its vmcnt(0)
    // wait would serialize on them)
    __builtin_amdgcn_sched_barrier(0);

    // ---- overlapped with the exchange flight ----
    // wave 7 polls (ACQUIRE) while waves 0-2 run the FC for step t-1
    if (big && wv == 7 && lane < NB) {
      u64* slot = &mail[(r & 1) * NB + lane];
      u64 v = __hip_atomic_load(slot, __ATOMIC_ACQUIRE, __HIP_MEMORY_SCOPE_AGENT);
      while ((unsigned)(v >> 32) != (unsigned)r) {
        __builtin_amdgcn_s_sleep(2);
        v = __hip_atomic_load(slot, __ATOMIC_ACQUIRE, __HIP_MEMORY_SCOPE_AGENT);
      }
      SM[O_DELT + lane] = __uint_as_float((unsigned)v);
    }
    float xr = 0.f;
    if (tid < IDM && t + 1 < TST) xr = myx[(size_t)(t + 1) * IDM + tid];
    if (t > 0 && tid < 160) {     // FC for step t-1 (reads GEX from prev iter)
      const int cls = tid >> 4, p = tid & 15;
      float pt = 0.f;
      #pragma unroll
      for (int i = 0; i < 16; ++i) {
        const int k = p + 16 * i;
        pt = fmaf(SM[O_WFC + cls * 264 + k], SM[O_GEX + k], pt);
      }
      pt = sum16(pt);
      if (p == 0) dout[(size_t)(b * TST + (t - 1)) * NCLS + cls] = pt + SM[O_BFC + cls];
    }
    __syncthreads();                                        // B2

    // ================= attention weights + per-wave-private gather =============
    const int tp = (wv << 6) | lane;    // this thread's buffer position
    float wval = 0.f; bool pred = false;
    if (big) {
      if (tp < r) {
        const float sc = s_h + SM[O_SBUF + tp];
        wval = fmaxf(sc - SM[O_DELT + ((b * r + tp) & (NB - 1))], 0.f);
        pred = (wval > 0.f) && (tp > 0);
      }
    } else {
      // r <= 5: all valid positions live in wave 0; softmax
      float scv = (tp < r) ? (s_h + SM[O_SBUF + tp]) : -3e38f;
      float mx = scv;
      mx = fmaxf(mx, __shfl_xor(mx, 1, 64));  mx = fmaxf(mx, __shfl_xor(mx, 2, 64));
      mx = fmaxf(mx, __shfl_xor(mx, 4, 64));  mx = fmaxf(mx, __shfl_xor(mx, 8, 64));
      mx = fmaxf(mx, __shfl_xor(mx, 16, 64)); mx = fmaxf(mx, __shfl_xor(mx, 32, 64));
      if (tp < r) {
        wval = __builtin_amdgcn_exp2f(LOG2E * (scv - mx));
        pred = (tp > 0);
      }
    }
    const float wsp = wave_sum(wval);        // includes t'=0 weight (denominator)
    if (lane == 0) SM[O_MISC + 8 + wv] = wsp;

    // gather THIS wave's nonzeros (no inter-wave handoff, no extra barrier)
    float g0 = 0.f, g1 = 0.f;
    u64 m = __ballot((int)pred);
    while (m) {
      const int l = __builtin_ctzll(m); m &= m - 1;
      const float wgt = __shfl(wval, l, 64);
      const int row = (wv << 6) + l - 1;     // buf[tp] == hs row tp-1
      const float2 v = reinterpret_cast<const float2*>(
          hsout + (size_t)(b * TST + row) * HDM)[lane];
      g0 = fmaf(wgt, v.x, g0);
      g1 = fmaf(wgt, v.y, g1);
    }
    reinterpret_cast<float2*>(SM + O_RED + wv * HDM)[lane] = make_float2(g0, g1);
    __syncthreads();                                        // B3

    // ================= finalize h, stores =================
    float wsum = 0.f;
    #pragma unroll
    for (int i = 0; i < 8; ++i) wsum += SM[O_MISC + 8 + i];
    const float inv = 1.0f / (wsum + (big ? EPSF : 0.0f));
    float attn = 0.f;
    #pragma unroll
    for (int wv2 = 0; wv2 < 8; ++wv2) attn += SM[O_RED + wv2 * HDM + j];
    attn *= inv;
    const float hf = hc + attn;
    if (s == 0) {
      SM[O_ACT + IDM + j] = hf;     // h for next step's gates
      SM[O_GEX + j] = hf;           // FC feature
      SM[O_GEX + HDM + j] = attn;
      hsout[(size_t)(b * TST + t) * HDM + j] = hf;
    }
    if (tid < IDM && t + 1 < TST) SM[O_ACT + tid] = xr;
    const float tbv = wave_sum((s == 0) ? tanh_f(hf) * wt1 : 0.f);
    if (lane == 0) SM[O_MISC + 16 + wv] = tbv;
    __syncthreads();                                        // B4 (loop end)
  }

  // final FC for t = 383
  if (tid < 160) {
    const int cls = tid >> 4, p = tid & 15;
    float pt = 0.f;
    #pragma unroll
    for (int i = 0; i < 16; ++i) {
      const int k = p + 16 * i;
      pt = fmaf(SM[O_WFC + cls * 264 + k], SM[O_GEX + k], pt);
    }
    pt = sum16(pt);
    if (p == 0) dout[(size_t)(b * TST + (TST - 1)) * NCLS + cls] = pt + SM[O_BFC + cls];
  }
}

extern "C" void kernel_launch(void* const* d_in, const int* in_sizes, int n_in,
                              void* d_out, int out_size, void* d_ws, size_t ws_size,
                              hipStream_t stream) {
  const float* x   = (const float*)d_in[0];
  const float* Wih = (const float*)d_in[1];
  const float* Whh = (const float*)d_in[2];
  const float* bih = (const float*)d_in[3];
  const float* bhh = (const float*)d_in[4];
  const float* wt  = (const float*)d_in[5];
  const float* Wfc = (const float*)d_in[6];
  const float* bfc = (const float*)d_in[7];
  sab_kernel<<<dim3(NB), dim3(512), 0, stream>>>(
      x, Wih, Whh, bih, bhh, wt, Wfc, bfc, (float*)d_out, (u64*)d_ws);
}

// Round 6
// 1900.154 us; speedup vs baseline: 2.4962x; 2.1075x over previous
//
#include <hip/hip_runtime.h>
#include <stdint.h>

typedef unsigned long long u64;

#define NB   32
#define TST  384
#define IDM  64
#define HDM  128
#define NCLS 10
#define EPSF 1e-7f
#define LOG2E 1.44269504088896340736f

// LDS layout (float offsets) — round-1 layout; gate exchange moved to O_RED
#define O_SBUF 0      // 385 (pad->388)  cached s_buf[t']
#define O_WLDS 388    // 388             attention weights w[t']
#define O_ACT  776    // 192             [x_t(64) | h(128)] activations
#define O_GEX  968    // 512             FC feature [h|attn] in [0..256); IDX ints in [0..384)
#define O_RED  1480   // 1024            gate exchange (S1, [0..512)) + attn partials (S6, 8x128)
#define O_DELT 2504   // 32              deltas from all batches
#define O_WFC  2536   // 10*264 = 2640   padded W_fc
#define O_BFC  5176   // 12
#define O_MISC 5188   // 32
#define SMTOT  5220

__device__ __forceinline__ float sigm(float x) {
  return 1.0f / (1.0f + __builtin_amdgcn_exp2f(-LOG2E * x));
}
__device__ __forceinline__ float tanh_f(float x) {
  return 1.0f - 2.0f / (1.0f + __builtin_amdgcn_exp2f(2.0f * LOG2E * x));
}

// System-scope (sc0 sc1) 8B mailbox ops: bypass L1/L2, meet at the memory-side
// Infinity Cache. No buffer_inv / wbl2 side effects (the agent-scope
// acquire/release poll was invalidating the whole XCD L2 every iteration).
__device__ __forceinline__ void mail_store(u64* p, u64 v) {
  asm volatile("global_store_dwordx2 %0, %1, off sc0 sc1"
               :: "v"(p), "v"(v) : "memory");
}
__device__ __forceinline__ u64 mail_load(u64* p) {
  u64 v;
  asm volatile("global_load_dwordx2 %0, %1, off sc0 sc1\n\t"
               "s_waitcnt vmcnt(0)"
               : "=v"(v) : "v"(p) : "memory");
  return v;
}

__global__ __launch_bounds__(512, 2)
void sab_kernel(const float* __restrict__ x, const float* __restrict__ Wih,
                const float* __restrict__ Whh, const float* __restrict__ bihp,
                const float* __restrict__ bhhp, const float* __restrict__ wtp,
                const float* __restrict__ Wfcp, const float* __restrict__ bfcp,
                float* __restrict__ dout, u64* __restrict__ mail) {
  __shared__ __align__(16) float SM[SMTOT];
  int* IMISC = (int*)(SM + O_MISC);   // ints at slots 16..23 (counts)
  int* IDX   = (int*)(SM + O_GEX);    // compacted t' indices (reuses GEX)

  const int tid  = threadIdx.x;
  const int lane = tid & 63;
  const int wvid = tid >> 6;
  const int b    = blockIdx.x;
  const int go   = tid >> 3;          // gate octet 0..63
  const int kc   = tid & 7;           // K-chunk 0..7 (24 cols each)

  float* hsout = dout + (size_t)NB * TST * NCLS;     // hs region == attention buf
  const float* myx = x + (size_t)b * TST * IDM;

  // ---- preload weight sub-block: rows 8*go..8*go+7, cols 24*kc..24*kc+23 ----
  float w[8][24];
  #pragma unroll
  for (int i = 0; i < 8; ++i) {
    const int g = 8 * go + i;
    #pragma unroll
    for (int j = 0; j < 24; ++j) {
      const int k = 24 * kc + j;
      const float* sp = (k < IDM) ? (Wih + g * IDM + k) : (Whh + g * HDM + (k - IDM));
      w[i][j] = *sp;
    }
  }
  const float bias = bihp[tid] + bhhp[tid];
  float wt0 = 0.f, wt1 = 0.f, cst = 0.f;
  if (tid < HDM) { wt0 = wtp[tid]; wt1 = wtp[HDM + tid]; }

  // incremental top-5 of s_buf (thread 0 only meaningful); s_buf[0]=0 pre-inserted
  float t5a = 0.f, t5b = -3e38f, t5c = -3e38f, t5d = -3e38f, t5e = -3e38f;

  // ---- init LDS ----
  for (int idx = tid; idx < NCLS * 256; idx += 512) {
    const int c = idx >> 8, k = idx & 255;
    SM[O_WFC + c * 264 + k] = Wfcp[idx];
  }
  if (tid < NCLS) SM[O_BFC + tid] = bfcp[tid];
  if (tid < HDM) SM[O_ACT + 64 + tid] = 0.f;   // h0 = 0
  if (tid < IDM) SM[O_ACT + tid] = myx[tid];   // x_0
  if (tid == 0) {
    SM[O_SBUF] = 0.f;
    mail_store(&mail[b], 0ull);
    mail_store(&mail[NB + b], 0ull);
  }
  __syncthreads();

  float hc = 0.f;
  for (int t = 0; t < TST; ++t) {
    const int r = t + 1;
    const bool big = (r > 5);

    // ================= gates: g = [x|h] @ W^T + bias =================
    float acc[8] = {0,0,0,0,0,0,0,0};
    {
      const float4* a4 = reinterpret_cast<const float4*>(SM + O_ACT + kc * 24);
      #pragma unroll
      for (int m = 0; m < 6; ++m) {
        const float4 av = a4[m];
        #pragma unroll
        for (int i = 0; i < 8; ++i) {
          acc[i] = fmaf(av.x, w[i][4*m+0], acc[i]);
          acc[i] = fmaf(av.y, w[i][4*m+1], acc[i]);
          acc[i] = fmaf(av.z, w[i][4*m+2], acc[i]);
          acc[i] = fmaf(av.w, w[i][4*m+3], acc[i]);
        }
      }
    }
    #pragma unroll
    for (int i = 0; i < 8; ++i) {   // butterfly over the 8 kc lanes
      acc[i] += __shfl_xor(acc[i], 1, 64);
      acc[i] += __shfl_xor(acc[i], 2, 64);
      acc[i] += __shfl_xor(acc[i], 4, 64);
    }
    float pre = acc[0];
    #pragma unroll
    for (int i = 1; i < 8; ++i) if (kc == i) pre = acc[i];  // this thread's gate = tid
    pre += bias;
    const bool tg = (tid >= 256) && (tid < 384);            // gg gates -> tanh
    SM[O_RED + tid] = tg ? tanh_f(pre) : sigm(pre);         // gate exchange in RED
    __syncthreads();                                        // S1

    // ================= LSTM cell (threads 0..127) =================
    float th = 0.f;
    if (tid < HDM) {
      const float iv = SM[O_RED + tid];
      const float fv = SM[O_RED + 128 + tid];
      const float gv = SM[O_RED + 256 + tid];
      const float ov = SM[O_RED + 384 + tid];
      cst = fv * cst + iv * gv;
      hc  = ov * tanh_f(cst);
      th  = tanh_f(hc) * wt0;        // partial of s_h
    }
    #pragma unroll
    for (int s = 1; s < 64; s <<= 1) th += __shfl_xor(th, s, 64);
    if (lane == 0 && tid < HDM) SM[O_MISC + wvid] = th;
    __syncthreads();                                        // S2
    const float s_h = SM[O_MISC] + SM[O_MISC + 1];

    // ---- publish delta (tid0, sc0sc1 write-through) ----
    if (big && tid == 0) {
      const float delta = t5e + s_h + EPSF;                 // 5th-largest score + eps
      const u64 pv = (((u64)(unsigned)r) << 32) | (u64)__float_as_uint(delta);
      mail_store(&mail[(r & 1) * NB + b], pv);
    }

    // ---- overlapped with the exchange flight: x-prefetch + FC(t-1) ----
    float xr = 0.f;
    if (tid < IDM && t + 1 < TST) xr = myx[(size_t)(t + 1) * IDM + tid];
    if (t > 0 && tid < 160) {       // reads GEX written at finalize of step t-1
      const int cls = tid >> 4, p = tid & 15;
      float pt = 0.f;
      #pragma unroll
      for (int i = 0; i < 16; ++i) {
        const int k = p + 16 * i;
        pt = fmaf(SM[O_WFC + cls * 264 + k], SM[O_GEX + k], pt);
      }
      #pragma unroll
      for (int s2 = 1; s2 < 16; s2 <<= 1) pt += __shfl_xor(pt, s2, 64);
      if (p == 0) dout[((size_t)(b * TST + (t - 1))) * NCLS + cls] = pt + SM[O_BFC + cls];
    }

    // ---- poll on wave 7 (sc0sc1 loads: no cache invalidation) ----
    if (big && wvid == 7 && lane < NB) {
      u64* slot = &mail[(r & 1) * NB + lane];
      u64 v = mail_load(slot);
      while ((unsigned)(v >> 32) != (unsigned)r) {
        __builtin_amdgcn_s_sleep(2);
        v = mail_load(slot);
      }
      SM[O_DELT + lane] = __uint_as_float((unsigned)v);
    }
    __syncthreads();                                        // S3

    // ================= attention weights =================
    float wval = 0.f;
    bool pred = false;
    if (big) {
      if (tid < r) {
        const float sc = s_h + SM[O_SBUF + tid];
        wval = fmaxf(sc - SM[O_DELT + ((b * r + tid) & (NB - 1))], 0.f);
        SM[O_WLDS + tid] = wval;
        pred = (wval > 0.f) && (tid > 0);   // t'=0 row is zeros: no contribution
      }
    } else {
      float scv = (tid < r) ? (s_h + SM[O_SBUF + tid]) : -3e38f;
      float mx = scv;
      #pragma unroll
      for (int s = 1; s < 64; s <<= 1) mx = fmaxf(mx, __shfl_xor(mx, s, 64));
      if (tid < r) {
        wval = __builtin_amdgcn_exp2f(LOG2E * (scv - mx));
        SM[O_WLDS + tid] = wval;
        pred = (tid > 0);
      }
    }
    float wsp = wval;
    #pragma unroll
    for (int s = 1; s < 64; s <<= 1) wsp += __shfl_xor(wsp, s, 64);
    if (lane == 0) SM[O_MISC + 2 + wvid] = wsp;
    const u64 bmask = __ballot((int)pred);
    if (lane == 0) IMISC[16 + wvid] = (int)__popcll(bmask);
    __syncthreads();                                        // S4

    float wsum = 0.f;
    #pragma unroll
    for (int i = 0; i < 8; ++i) wsum += SM[O_MISC + 2 + i];
    const float inv = 1.0f / (wsum + (big ? EPSF : 0.f));
    int wbase = 0, nnz = 0;
    #pragma unroll
    for (int i = 0; i < 8; ++i) {
      const int c = IMISC[16 + i];
      if (i < wvid) wbase += c;
      nnz += c;
    }
    if (pred) {
      const int pos = wbase + (int)__popcll(bmask & ((1ull << lane) - 1ull));
      IDX[pos] = tid;
    }
    __syncthreads();                                        // S5

    // ================= attn_c: sparse gather over buf (== hs rows) =================
    const int j8 = tid & 15, q = tid >> 4;
    float ac[8] = {0,0,0,0,0,0,0,0};
    for (int ii = q; ii < nnz; ii += 32) {
      const int tp = IDX[ii];                                // t' index (>=1)
      const float wgt = SM[O_WLDS + tp] * inv;
      const float* bp = hsout + ((size_t)(b * TST + tp - 1)) * HDM + j8 * 8;
      const float4 v0 = *reinterpret_cast<const float4*>(bp);
      const float4 v1 = *reinterpret_cast<const float4*>(bp + 4);
      ac[0] = fmaf(wgt, v0.x, ac[0]); ac[1] = fmaf(wgt, v0.y, ac[1]);
      ac[2] = fmaf(wgt, v0.z, ac[2]); ac[3] = fmaf(wgt, v0.w, ac[3]);
      ac[4] = fmaf(wgt, v1.x, ac[4]); ac[5] = fmaf(wgt, v1.y, ac[5]);
      ac[6] = fmaf(wgt, v1.z, ac[6]); ac[7] = fmaf(wgt, v1.w, ac[7]);
    }
    #pragma unroll
    for (int i = 0; i < 8; ++i) {     // reduce the 4 q-groups inside each wave
      ac[i] += __shfl_xor(ac[i], 16, 64);
      ac[i] += __shfl_xor(ac[i], 32, 64);
    }
    if ((q & 3) == 0) {
      float4* r4 = reinterpret_cast<float4*>(SM + O_RED + wvid * 128 + j8 * 8);
      r4[0] = make_float4(ac[0], ac[1], ac[2], ac[3]);
      r4[1] = make_float4(ac[4], ac[5], ac[6], ac[7]);
    }
    __syncthreads();                                        // S6

    // ================= finalize h, write outputs =================
    float tb = 0.f;
    if (tid < HDM) {
      float s = 0.f;
      #pragma unroll
      for (int wv2 = 0; wv2 < 8; ++wv2) s += SM[O_RED + wv2 * 128 + tid];
      const float hf = hc + s;
      hsout[((size_t)(b * TST + t)) * HDM + tid] = hf;
      SM[O_ACT + 64 + tid] = hf;       // h for next step's gates
      SM[O_GEX + tid] = hf;            // FC input [h | attn_c]
      SM[O_GEX + 128 + tid] = s;
      tb = tanh_f(hf) * wt1;           // partial of s_buf[r]
    }
    if (tid < IDM && t + 1 < TST) SM[O_ACT + tid] = xr;
    #pragma unroll
    for (int s2 = 1; s2 < 64; s2 <<= 1) tb += __shfl_xor(tb, s2, 64);
    if (lane == 0 && tid < HDM) SM[O_MISC + 24 + wvid] = tb;
    __syncthreads();                                        // S7

    if (tid == 0 && r < TST) {
      const float sb = SM[O_MISC + 24] + SM[O_MISC + 25];
      SM[O_SBUF + r] = sb;
      if (sb > t5e) {                  // maintain 5 largest s_buf values
        if (sb > t5a)      { t5e=t5d; t5d=t5c; t5c=t5b; t5b=t5a; t5a=sb; }
        else if (sb > t5b) { t5e=t5d; t5d=t5c; t5c=t5b; t5b=sb; }
        else if (sb > t5c) { t5e=t5d; t5d=t5c; t5c=sb; }
        else if (sb > t5d) { t5e=t5d; t5d=sb; }
        else               { t5e=sb; }
      }
    }
  }

  // final FC for t = 383 (reads GEX written at last finalize)
  if (tid < 160) {
    const int cls = tid >> 4, p = tid & 15;
    float pt = 0.f;
    #pragma unroll
    for (int i = 0; i < 16; ++i) {
      const int k = p + 16 * i;
      pt = fmaf(SM[O_WFC + cls * 264 + k], SM[O_GEX + k], pt);
    }
    #pragma unroll
    for (int s2 = 1; s2 < 16; s2 <<= 1) pt += __shfl_xor(pt, s2, 64);
    if (p == 0) dout[((size_t)(b * TST + (TST - 1))) * NCLS + cls] = pt + SM[O_BFC + cls];
  }
}

extern "C" void kernel_launch(void* const* d_in, const int* in_sizes, int n_in,
                              void* d_out, int out_size, void* d_ws, size_t ws_size,
                              hipStream_t stream) {
  const float* x   = (const float*)d_in[0];
  const float* Wih = (const float*)d_in[1];
  const float* Whh = (const float*)d_in[2];
  const float* bih = (const float*)d_in[3];
  const float* bhh = (const float*)d_in[4];
  const float* wt  = (const float*)d_in[5];
  const float* Wfc = (const float*)d_in[6];
  const float* bfc = (const float*)d_in[7];
  sab_kernel<<<dim3(NB), dim3(512), 0, stream>>>(
      x, Wih, Whh, bih, bhh, wt, Wfc, bfc, (float*)d_out, (u64*)d_ws);
}